// Round 8
// baseline (131.903 us; speedup 1.0000x reference)
//
#include <hip/hip_runtime.h>
#include <cmath>

// PositionIntervalLoss: B=65536 rows, F=300. TWO rows per wave (ILP=2 on all
// latency chains: gather loads, the 6-stage fp64 wave scan, fence, epilogue),
// 4 waves/block -> 8 rows/block, LDS 40960 B -> 4 blocks/CU = 32 rows/CU.
// Lane l (<60) owns elements [5l,5l+5) of each of its 2 rows.
// fp64 blur + fp64 prefix sums are REQUIRED (round-3: fp32 prefix error
// ~1e-4 flips (sm <> +-1) comparisons; fp32 blur would flip strict-peak
// comparisons). No __syncthreads: each wave owns its rows' LDS slices;
// same-wave DS ops execute in order -> wave-local waitcnt fence suffices.

constexpr int FLEN = 300;
constexpr int RPW  = 2;                // rows per wave
constexpr int WPB  = 4;                // waves per block
constexpr int RPB  = RPW * WPB;        // 8 rows per block
constexpr int SMAX = 152;

__global__ __launch_bounds__(256, 4)
void pil_kernel(const float* __restrict__ in, float* __restrict__ out,
                double bk0, double bk1, double bk2, double bk3)
{
    const int w    = threadIdx.x >> 6;
    const int lane = threadIdx.x & 63;
    const int row0 = blockIdx.x * RPB + w * RPW;

    __shared__ double2        eg_s[RPB][FLEN];   // eg[t]=(sum_{u<t} e_u, sum_{u<t} e_u*fr_u)
    __shared__ unsigned short ps_s[RPB][SMAX];   // sorted peak positions

    const int    base = lane * 5;
    const bool   act  = (lane < 60);
    const int    bC   = act ? base : 295;        // clamp OOB lanes (unused)
    const float  NINF = -__builtin_inff();

    // ---- phase 1: both rows' raw loads issued back-to-back (MLP=10) ----
    float rv[RPW][5];
    #pragma unroll
    for (int q = 0; q < RPW; ++q) {
        const float* rin = in + (size_t)(row0 + q) * FLEN;
        rv[q][0] = rin[bC+0]; rv[q][1] = rin[bC+1]; rv[q][2] = rin[bC+2];
        rv[q][3] = rin[bC+3]; rv[q][4] = rin[bC+4];
    }

    // ---- phase 2: halo shfl + fp64 blur, interleaved across rows ----
    float f[RPW][5];
    #pragma unroll
    for (int q = 0; q < RPW; ++q) {
        float l2 = __shfl_up(rv[q][2], 1), l3 = __shfl_up(rv[q][3], 1), l4 = __shfl_up(rv[q][4], 1);
        float h0 = __shfl_down(rv[q][0], 1), h1 = __shfl_down(rv[q][1], 1), h2 = __shfl_down(rv[q][2], 1);
        if (lane == 0)  { l2 = 0.f; l3 = 0.f; l4 = 0.f; }   // conv 'SAME' zero pad
        if (lane >= 59) { h0 = 0.f; h1 = 0.f; h2 = 0.f; }
        const double d0=(double)l2, d1=(double)l3, d2=(double)l4, d3=(double)rv[q][0],
                     d4=(double)rv[q][1], d5=(double)rv[q][2], d6=(double)rv[q][3],
                     d7=(double)rv[q][4], d8=(double)h0, d9=(double)h1, d10=(double)h2;
        f[q][0] = (float)fma(bk0, d0+d6,  fma(bk1, d1+d5, fma(bk2, d2+d4, bk3*d3)));
        f[q][1] = (float)fma(bk0, d1+d7,  fma(bk1, d2+d6, fma(bk2, d3+d5, bk3*d4)));
        f[q][2] = (float)fma(bk0, d2+d8,  fma(bk1, d3+d7, fma(bk2, d4+d6, bk3*d5)));
        f[q][3] = (float)fma(bk0, d3+d9,  fma(bk1, d4+d8, fma(bk2, d5+d7, bk3*d6)));
        f[q][4] = (float)fma(bk0, d4+d10, fma(bk1, d5+d9, fma(bk2, d6+d8, bk3*d7)));
    }

    // ---- phase 3: strict peaks + ballot/mbcnt compaction, per row ----
    int P[RPW];
    #pragma unroll
    for (int q = 0; q < RPW; ++q) {
        unsigned short* ps = ps_s[w * RPW + q];
        float fm1 = __shfl_up(f[q][4], 1);
        float fp1 = __shfl_down(f[q][0], 1);
        if (lane == 0)  fm1 = NINF;
        if (lane >= 59) fp1 = NINF;
        bool p[5];
        float lft = fm1;
        #pragma unroll
        for (int j = 0; j < 5; ++j) {
            float rgt = (j < 4) ? f[q][j+1] : fp1;
            p[j] = act && (f[q][j] > lft) && (f[q][j] > rgt);
            lft = f[q][j];
        }
        unsigned long long b0 = __ballot(p[0]), b1 = __ballot(p[1]), b2 = __ballot(p[2]),
                           b3 = __ballot(p[3]), b4 = __ballot(p[4]);
        int off = 0;
        off = __builtin_amdgcn_mbcnt_lo((unsigned)b0, off);
        off = __builtin_amdgcn_mbcnt_hi((unsigned)(b0 >> 32), off);
        off = __builtin_amdgcn_mbcnt_lo((unsigned)b1, off);
        off = __builtin_amdgcn_mbcnt_hi((unsigned)(b1 >> 32), off);
        off = __builtin_amdgcn_mbcnt_lo((unsigned)b2, off);
        off = __builtin_amdgcn_mbcnt_hi((unsigned)(b2 >> 32), off);
        off = __builtin_amdgcn_mbcnt_lo((unsigned)b3, off);
        off = __builtin_amdgcn_mbcnt_hi((unsigned)(b3 >> 32), off);
        off = __builtin_amdgcn_mbcnt_lo((unsigned)b4, off);
        off = __builtin_amdgcn_mbcnt_hi((unsigned)(b4 >> 32), off);
        P[q] = __popcll(b0) + __popcll(b1) + __popcll(b2) + __popcll(b3) + __popcll(b4);
        #pragma unroll
        for (int j = 0; j < 5; ++j)
            if (p[j]) ps[off++] = (unsigned short)(base + j);
    }

    // ---- phase 4: exp/freq + intra-lane fp64 inclusive prefixes ----
    float fr5[5];
    #pragma unroll
    for (int j = 0; j < 5; ++j)
        fr5[j] = fmaf((float)(base + j - 99), 0.02f, -1.0f);   // ((i+1)-100)/100*2-1

    double cE[RPW][5], cG[RPW][5], tE[RPW], tG[RPW];
    #pragma unroll
    for (int q = 0; q < RPW; ++q) {
        double aE = 0.0, aG = 0.0;
        #pragma unroll
        for (int j = 0; j < 5; ++j) {
            int  i = base + j;
            bool v = act && (i < FLEN - 1);
            float e  = v ? __expf(f[q][j]) : 0.f;   // |f|<~3: unstable softmax identical
            double de = (double)e;
            aE += de;
            aG  = fma(de, (double)fr5[j], aG);
            cE[q][j] = aE; cG[q][j] = aG;
        }
        tE[q] = aE; tG[q] = aG;
    }

    // ---- phase 5: two fp64 wave scans, stage-interleaved (chains overlap) ----
    double sE[RPW], sG[RPW];
    #pragma unroll
    for (int q = 0; q < RPW; ++q) { sE[q] = tE[q]; sG[q] = tG[q]; }
    #pragma unroll
    for (int d = 1; d < 64; d <<= 1) {
        #pragma unroll
        for (int q = 0; q < RPW; ++q) {
            double a = __shfl_up(sE[q], d), b = __shfl_up(sG[q], d);
            if (lane >= d) { sE[q] += a; sG[q] += b; }
        }
    }

    // ---- phase 6: scatter inclusive prefixes to LDS ----
    #pragma unroll
    for (int q = 0; q < RPW; ++q) {
        double2* eg = eg_s[w * RPW + q];
        const double xE = sE[q] - tE[q], xG = sG[q] - tG[q];
        if (lane == 63) eg[0] = make_double2(0.0, 0.0);
        #pragma unroll
        for (int j = 0; j < 5; ++j) {
            int i = base + j;
            if (act && i <= FLEN - 2)
                eg[i + 1] = make_double2(xE + cE[q][j], xG + cG[q][j]);
        }
    }

    // ---- wave-local LDS fence (wave is sole owner of its rows' slices) ----
    __builtin_amdgcn_wave_barrier();
    __asm__ volatile("s_waitcnt lgkmcnt(0)" ::: "memory");
    __builtin_amdgcn_wave_barrier();

    // ---- phase 7: per-segment softargmax = prefix difference; epilogue ----
    #pragma unroll
    for (int q = 0; q < RPW; ++q) {
        double2*        eg = eg_s[w * RPW + q];
        unsigned short* ps = ps_s[w * RPW + q];
        const int nseg = (P[q] > 0) ? P[q] : 1;
        float sum_in = 0.f; int any_in = 0;
        for (int s = lane; s < nseg; s += 64) {
            int im = (s > 0) ? s - 1 : 0;
            int ip = (s < P[q] - 1) ? s + 1 : im;
            int pm = ps[im], pc = ps[(P[q] > 0) ? s : 0], pn = ps[ip];
            int lo = (s == 0)        ? 0        : ((pm + pc) >> 1);
            int hi = (s == nseg - 1) ? FLEN - 1 : ((pc + pn) >> 1);
            double2 a = eg[lo], b = eg[hi];
            float den = (float)(b.x - a.x);     // exact to ~1e-13, > 0
            float num = (float)(b.y - a.y);
            float sm  = num / den;
            bool  ii  = (sm > -1.0f) && (sm < 1.0f);
            if (ii) { sum_in -= sm * sm; any_in = 1; }
        }
        if (__ballot(any_in) != 0ull) {
            #pragma unroll
            for (int d = 32; d >= 1; d >>= 1) sum_in += __shfl_xor(sum_in, d);
            if (lane == 0) out[row0 + q] = sum_in;
        } else {
            // rare fallback (wave-uniform): recompute, track two largest nsq
            float m1 = NINF, m2 = NINF;
            for (int s = lane; s < nseg; s += 64) {
                int im = (s > 0) ? s - 1 : 0;
                int ip = (s < P[q] - 1) ? s + 1 : im;
                int pm = ps[im], pc = ps[(P[q] > 0) ? s : 0], pn = ps[ip];
                int lo = (s == 0)        ? 0        : ((pm + pc) >> 1);
                int hi = (s == nseg - 1) ? FLEN - 1 : ((pc + pn) >> 1);
                double2 a = eg[lo], b = eg[hi];
                float den = (float)(b.x - a.x);
                float num = (float)(b.y - a.y);
                float sm  = num / den;
                float nsq = -(sm * sm);
                if (nsq > m1) { m2 = m1; m1 = nsq; } else { m2 = fmaxf(m2, nsq); }
            }
            #pragma unroll
            for (int d = 32; d >= 1; d >>= 1) {
                float o1 = __shfl_xor(m1, d);
                float o2 = __shfl_xor(m2, d);
                float n1 = fmaxf(m1, o1);
                float n2 = fmaxf(fminf(m1, o1), fmaxf(m2, o2));
                m1 = n1; m2 = n2;
            }
            if (lane == 0) {
                float t2 = m1 + ((m2 > NINF) ? m2 : 0.0f);
                out[row0 + q] = t2;
            }
        }
    }
}

extern "C" void kernel_launch(void* const* d_in, const int* in_sizes, int n_in,
                              void* d_out, int out_size, void* d_ws, size_t ws_size,
                              hipStream_t stream) {
    const float* in  = (const float*)d_in[0];
    float*       out = (float*)d_out;
    const int B = in_sizes[0] / FLEN;          // 65536

    // Gaussian kernel sigma=2, l=7: double, normalized, rounded to fp32
    // (matching jnp.asarray(k/k.sum(), float32)), widened back to double.
    double k[7], s = 0.0;
    for (int t = 0; t < 7; ++t) {
        double x = -3.0 + (double)t;
        k[t] = exp(-0.5 * x * x / 4.0);
        s += k[t];
    }
    double bk0 = (double)(float)(k[0] / s);
    double bk1 = (double)(float)(k[1] / s);
    double bk2 = (double)(float)(k[2] / s);
    double bk3 = (double)(float)(k[3] / s);

    pil_kernel<<<B / RPB, 256, 0, stream>>>(in, out, bk0, bk1, bk2, bk3);
}

// Round 9
// 118.245 us; speedup vs baseline: 1.1155x; 1.1155x over previous
//
#include <hip/hip_runtime.h>
#include <cmath>

// PositionIntervalLoss: B=65536 rows, F=300. One wave per row, 4 rows/block
// (round-7 structure — best measured). Lane l (<60) owns elements [5l,5l+5).
// fp64 blur + fp64 prefix sums REQUIRED (fp32 prefix error ~1e-4 flips
// (sm <> +-1) comparisons — round-3 failure). Round-9 change: the fp64 wave
// scan uses DPP (row_shr + row_bcast) instead of shfl/ds_bpermute — pure
// VALU, ~5x shorter latency chain, 24 fewer LDS round-trips per row.

constexpr int FLEN = 300;
constexpr int RPB  = 4;
constexpr int SMAX = 152;

// DPP-move with identity 0 for unselected/invalid lanes (scan building block).
template <int CTRL, int RMASK>
__device__ __forceinline__ double dpp0_f64(double x) {
    union { double d; int i[2]; } u, r;
    u.d = x;
    r.i[0] = __builtin_amdgcn_update_dpp(0, u.i[0], CTRL, RMASK, 0xf, false);
    r.i[1] = __builtin_amdgcn_update_dpp(0, u.i[1], CTRL, RMASK, 0xf, false);
    return r.d;
}
template <int CTRL, int RMASK>
__device__ __forceinline__ float dpp0_f32(float x) {
    union { float f; int i; } u, r;
    u.f = x;
    r.i = __builtin_amdgcn_update_dpp(0, u.i, CTRL, RMASK, 0xf, false);
    return r.f;
}

__global__ __launch_bounds__(256, 8)
void pil_kernel(const float* __restrict__ in, float* __restrict__ out,
                double bk0, double bk1, double bk2, double bk3)
{
    const int w    = threadIdx.x >> 6;
    const int lane = threadIdx.x & 63;
    const int row  = blockIdx.x * RPB + w;

    __shared__ double2        eg_s[RPB][FLEN];   // eg[t]=(sum_{u<t} e_u, sum_{u<t} e_u*fr_u)
    __shared__ unsigned short ps_s[RPB][SMAX];   // sorted peak positions

    double2*        eg = eg_s[w];
    unsigned short* ps = ps_s[w];

    const float* rin  = in + (size_t)row * FLEN;
    const int    base = lane * 5;
    const bool   act  = (lane < 60);
    const int    bC   = act ? base : 295;          // clamp OOB lanes (unused)

    // ---- load own 5 raw values; halo via shfl ----
    float r0 = rin[bC+0], r1 = rin[bC+1], r2 = rin[bC+2], r3 = rin[bC+3], r4 = rin[bC+4];
    float l2 = __shfl_up(r2, 1), l3 = __shfl_up(r3, 1), l4 = __shfl_up(r4, 1);
    float h0 = __shfl_down(r0, 1), h1 = __shfl_down(r1, 1), h2 = __shfl_down(r2, 1);
    if (lane == 0)  { l2 = 0.f; l3 = 0.f; l4 = 0.f; }   // conv 'SAME' zero pad
    if (lane >= 59) { h0 = 0.f; h1 = 0.f; h2 = 0.f; }

    // ---- 7-tap symmetric blur, fp64 FMA accumulate (fp32-rounded coeffs) ----
    const double d0=(double)l2, d1=(double)l3, d2=(double)l4, d3=(double)r0,
                 d4=(double)r1, d5=(double)r2, d6=(double)r3, d7=(double)r4,
                 d8=(double)h0, d9=(double)h1, d10=(double)h2;
    float f[5];
    f[0] = (float)fma(bk0, d0+d6,  fma(bk1, d1+d5, fma(bk2, d2+d4, bk3*d3)));
    f[1] = (float)fma(bk0, d1+d7,  fma(bk1, d2+d6, fma(bk2, d3+d5, bk3*d4)));
    f[2] = (float)fma(bk0, d2+d8,  fma(bk1, d3+d7, fma(bk2, d4+d6, bk3*d5)));
    f[3] = (float)fma(bk0, d3+d9,  fma(bk1, d4+d8, fma(bk2, d5+d7, bk3*d6)));
    f[4] = (float)fma(bk0, d4+d10, fma(bk1, d5+d9, fma(bk2, d6+d8, bk3*d7)));

    // ---- strict peaks (boundary = -inf sentinel) ----
    float fm1 = __shfl_up(f[4], 1);
    float fp1 = __shfl_down(f[0], 1);
    if (lane == 0)  fm1 = -__builtin_inff();
    if (lane >= 59) fp1 = -__builtin_inff();

    bool p[5];
    {
        float lft = fm1;
        #pragma unroll
        for (int j = 0; j < 5; ++j) {
            float rgt = (j < 4) ? f[j+1] : fp1;
            p[j] = act && (f[j] > lft) && (f[j] > rgt);
            lft = f[j];
        }
    }

    // ---- compaction: ballot + mbcnt (popcount of mask & lanemask_lt) ----
    unsigned long long b0 = __ballot(p[0]), b1 = __ballot(p[1]), b2 = __ballot(p[2]),
                       b3 = __ballot(p[3]), b4 = __ballot(p[4]);
    int off = 0;
    off = __builtin_amdgcn_mbcnt_lo((unsigned)b0, off);
    off = __builtin_amdgcn_mbcnt_hi((unsigned)(b0 >> 32), off);
    off = __builtin_amdgcn_mbcnt_lo((unsigned)b1, off);
    off = __builtin_amdgcn_mbcnt_hi((unsigned)(b1 >> 32), off);
    off = __builtin_amdgcn_mbcnt_lo((unsigned)b2, off);
    off = __builtin_amdgcn_mbcnt_hi((unsigned)(b2 >> 32), off);
    off = __builtin_amdgcn_mbcnt_lo((unsigned)b3, off);
    off = __builtin_amdgcn_mbcnt_hi((unsigned)(b3 >> 32), off);
    off = __builtin_amdgcn_mbcnt_lo((unsigned)b4, off);
    off = __builtin_amdgcn_mbcnt_hi((unsigned)(b4 >> 32), off);
    const int P = __popcll(b0) + __popcll(b1) + __popcll(b2) + __popcll(b3) + __popcll(b4);
    #pragma unroll
    for (int j = 0; j < 5; ++j)
        if (p[j]) ps[off++] = (unsigned short)(base + j);

    // ---- per-element exp / freq; intra-lane inclusive prefixes in fp64 ----
    double cE[5], cG[5];
    double tE = 0.0, tG = 0.0;
    #pragma unroll
    for (int j = 0; j < 5; ++j) {
        int  i = base + j;
        bool v = act && (i < FLEN - 1);
        float e  = v ? __expf(f[j]) : 0.f;    // |f|<~3: unstable softmax identical
        float fr = fmaf((float)(i - 99), 0.02f, -1.0f);   // ((i+1)-100)/100*2-1
        double de = (double)e;
        tE += de;
        tG  = fma(de, (double)fr, tG);
        cE[j] = tE; cG[j] = tG;
    }

    // ---- wave64 inclusive scan of lane totals: DPP (pure VALU) ----
    double sE = tE, sG = tG;
    sE += dpp0_f64<0x111, 0xf>(sE);  sG += dpp0_f64<0x111, 0xf>(sG);  // row_shr:1
    sE += dpp0_f64<0x112, 0xf>(sE);  sG += dpp0_f64<0x112, 0xf>(sG);  // row_shr:2
    sE += dpp0_f64<0x114, 0xf>(sE);  sG += dpp0_f64<0x114, 0xf>(sG);  // row_shr:4
    sE += dpp0_f64<0x118, 0xf>(sE);  sG += dpp0_f64<0x118, 0xf>(sG);  // row_shr:8
    sE += dpp0_f64<0x142, 0xa>(sE);  sG += dpp0_f64<0x142, 0xa>(sG);  // row_bcast:15 -> rows 1,3
    sE += dpp0_f64<0x143, 0xc>(sE);  sG += dpp0_f64<0x143, 0xc>(sG);  // row_bcast:31 -> rows 2,3
    const double xE = sE - tE, xG = sG - tG;   // exclusive prefix of lane totals

    if (lane == 63) eg[0] = make_double2(0.0, 0.0);
    #pragma unroll
    for (int j = 0; j < 5; ++j) {
        int i = base + j;
        if (act && i <= FLEN - 2)
            eg[i + 1] = make_double2(xE + cE[j], xG + cG[j]);
    }

    // ---- wave-local LDS fence (this wave is sole owner of its row slice;
    //      same-wave DS ops execute in order — no s_barrier needed) ----
    __builtin_amdgcn_wave_barrier();
    __asm__ volatile("s_waitcnt lgkmcnt(0)" ::: "memory");
    __builtin_amdgcn_wave_barrier();

    // ---- per-segment softargmax = prefix difference; O(1) per segment ----
    const int nseg = (P > 0) ? P : 1;
    float sum_in = 0.f; int any_in = 0;
    for (int s = lane; s < nseg; s += 64) {
        int im = (s > 0) ? s - 1 : 0;
        int ip = (s < P - 1) ? s + 1 : im;
        int pm = ps[im], pc = ps[(P > 0) ? s : 0], pn = ps[ip];
        int lo = (s == 0)        ? 0        : ((pm + pc) >> 1);
        int hi = (s == nseg - 1) ? FLEN - 1 : ((pc + pn) >> 1);
        double2 a = eg[lo], b = eg[hi];
        float den = (float)(b.x - a.x);         // exact to ~1e-13, > 0
        float num = (float)(b.y - a.y);
        float sm  = num / den;
        bool  ii  = (sm > -1.0f) && (sm < 1.0f);
        if (ii) { sum_in -= sm * sm; any_in = 1; }
    }

    // ---- common path: some segment in-interval (one ballot decides) ----
    if (__ballot(any_in) != 0ull) {
        // DPP scan-reduce: lane 63 ends with the wave total
        sum_in += dpp0_f32<0x111, 0xf>(sum_in);
        sum_in += dpp0_f32<0x112, 0xf>(sum_in);
        sum_in += dpp0_f32<0x114, 0xf>(sum_in);
        sum_in += dpp0_f32<0x118, 0xf>(sum_in);
        sum_in += dpp0_f32<0x142, 0xa>(sum_in);
        sum_in += dpp0_f32<0x143, 0xc>(sum_in);
        if (lane == 63) out[row] = sum_in;
    } else {
        // rare fallback (wave-uniform): recompute, track two largest nsq
        float m1 = -__builtin_inff(), m2 = -__builtin_inff();
        for (int s = lane; s < nseg; s += 64) {
            int im = (s > 0) ? s - 1 : 0;
            int ip = (s < P - 1) ? s + 1 : im;
            int pm = ps[im], pc = ps[(P > 0) ? s : 0], pn = ps[ip];
            int lo = (s == 0)        ? 0        : ((pm + pc) >> 1);
            int hi = (s == nseg - 1) ? FLEN - 1 : ((pc + pn) >> 1);
            double2 a = eg[lo], b = eg[hi];
            float den = (float)(b.x - a.x);
            float num = (float)(b.y - a.y);
            float sm  = num / den;
            float nsq = -(sm * sm);
            if (nsq > m1) { m2 = m1; m1 = nsq; } else { m2 = fmaxf(m2, nsq); }
        }
        #pragma unroll
        for (int d = 32; d >= 1; d >>= 1) {
            float o1 = __shfl_xor(m1, d);
            float o2 = __shfl_xor(m2, d);
            float n1 = fmaxf(m1, o1);
            float n2 = fmaxf(fminf(m1, o1), fmaxf(m2, o2));
            m1 = n1; m2 = n2;
        }
        if (lane == 0) {
            float t2 = m1 + ((m2 > -__builtin_inff()) ? m2 : 0.0f);
            out[row] = t2;
        }
    }
}

extern "C" void kernel_launch(void* const* d_in, const int* in_sizes, int n_in,
                              void* d_out, int out_size, void* d_ws, size_t ws_size,
                              hipStream_t stream) {
    const float* in  = (const float*)d_in[0];
    float*       out = (float*)d_out;
    const int B = in_sizes[0] / FLEN;          // 65536

    // Gaussian kernel sigma=2, l=7: double, normalized, rounded to fp32
    // (matching jnp.asarray(k/k.sum(), float32)), widened back to double.
    double k[7], s = 0.0;
    for (int t = 0; t < 7; ++t) {
        double x = -3.0 + (double)t;
        k[t] = exp(-0.5 * x * x / 4.0);
        s += k[t];
    }
    double bk0 = (double)(float)(k[0] / s);
    double bk1 = (double)(float)(k[1] / s);
    double bk2 = (double)(float)(k[2] / s);
    double bk3 = (double)(float)(k[3] / s);

    pil_kernel<<<B / RPB, 256, 0, stream>>>(in, out, bk0, bk1, bk2, bk3);
}